// Round 11
// baseline (1938.227 us; speedup 1.0000x reference)
//
#include <hip/hip_runtime.h>
#include <hip/hip_bf16.h>
#include <hip/hip_fp8.h>

// Problem constants
#define B_   4096
#define S_   64
#define D_   9
#define H_   128
#define HZ_  32
#define DT_  0.1f

// f32 region layout (float offsets). Regions overlap in TIME, never within a kernel.
#define OFF_WET    0          // slot hosts WeTm  (bf16, 16384 ush) [encoder only]
#define OFF_VET    16384      // 4096 f32 V_e^T   [encoder only]
#define OFF_WENCT  20480      // slot hosts WencTm (bf16, 81920 ush) [encoder only]
#define OFF_BENC   90624      // 512   [encoder only]
#define OFF_WDT    91136      // slot hosts WdTm (bf16, 32768 ush)
#define OFF_WDECT  123904     // slot hosts WdecTm (bf16, 147456 ush)
#define OFF_BDEC   259584     // 512   (live, dec_step)
#define OFF_WOUTT  260096     // 768   (live, dec_step)
#define OFF_VDT    260864     // slot hosts VdTm (bf16, 16384 ush) [attnenc MFMA B-frags]
#define OFF_DECD   277248     // slot hosts dG (524288 ush); rest of slot unused now
#define OFF_DECC   801536     // 524288 : live c-state f32 (cG)
#define F32_TOTAL  1325824
#define PREP_N     277248

// ushort region after f32 region: EH bf16 (33554432 ush) | AETf8 + EHf8 (33.5M bytes each) | adG

typedef __bf16 bf16x8 __attribute__((ext_vector_type(8)));
typedef float  f32x4  __attribute__((ext_vector_type(4)));

__device__ __forceinline__ float fast_tanh(float x) {
    float e = __expf(2.0f * x);
    return 1.0f - __fdividef(2.0f, e + 1.0f);
}
__device__ __forceinline__ float sigf(float x) {
    return __fdividef(1.0f, 1.0f + __expf(-x));
}
__device__ __forceinline__ float bf_lo(unsigned int u) { return __uint_as_float(u << 16); }
__device__ __forceinline__ float bf_hi(unsigned int u) { return __uint_as_float(u & 0xffff0000u); }
__device__ __forceinline__ float bfu2f(unsigned short u) { return __uint_as_float((unsigned int)u << 16); }
__device__ __forceinline__ unsigned short f2bfu(float f) {
    __hip_bfloat16 b = __float2bfloat16(f);
    return *(unsigned short*)&b;
}
__device__ __forceinline__ unsigned int pack_bf(float lo, float hi) {
    return (unsigned int)f2bfu(lo) | ((unsigned int)f2bfu(hi) << 16);
}
__device__ __forceinline__ float f8tof(unsigned int byte) {
    __hip_fp8_e4m3 t; t.__x = (unsigned char)byte; return (float)t;
}
__device__ __forceinline__ unsigned char f2f8(float f) {
    __hip_fp8_e4m3 q(f); return q.__x;
}
__device__ __forceinline__ unsigned int pack4_f8(float a, float b, float c, float d) {
    return (unsigned int)f2f8(a) | ((unsigned int)f2f8(b) << 8) |
           ((unsigned int)f2f8(c) << 16) | ((unsigned int)f2f8(d) << 24);
}

// ---------------------------------------------------------------- prep (f32 tables)
__global__ void prep_kernel(const float* __restrict__ Wih_e, const float* __restrict__ Whh_e,
    const float* __restrict__ bih_e, const float* __restrict__ bhh_e,
    const float* __restrict__ W_e, const float* __restrict__ V_e,
    const float* __restrict__ W_d, const float* __restrict__ V_d,
    const float* __restrict__ Wih_d, const float* __restrict__ Whh_d,
    const float* __restrict__ bih_d, const float* __restrict__ bhh_d,
    const float* __restrict__ W_out, float* __restrict__ ws) {
  for (int idx = blockIdx.x * blockDim.x + threadIdx.x; idx < PREP_N;
       idx += gridDim.x * blockDim.x) {
    int i = idx;
    if (i < 16384) { continue; }
    i -= 16384;
    if (i < 4096) { int s = i >> 6, t = i & 63; ws[OFF_VET + i] = V_e[t * 64 + s]; continue; }
    i -= 4096;
    if (i < 70144) { continue; }
    i -= 70144;
    if (i < 512) { ws[OFF_BENC + i] = bih_e[i] + bhh_e[i]; continue; }
    i -= 512;
    if (i < 32768) { continue; }
    i -= 32768;
    if (i < 135680) { continue; }
    i -= 135680;
    if (i < 512) { ws[OFF_BDEC + i] = bih_d[i] + bhh_d[i]; continue; }
    i -= 512;
    if (i < 768) { int k = i / 3, j = i % 3; ws[OFF_WOUTT + i] = W_out[j * 256 + k]; continue; }
  }
}

// ---------------------------------------------------------------- prep decoder MFMA weights
__global__ void prep_mfma_kernel(const float* __restrict__ W_d,
    const float* __restrict__ Wih_d, const float* __restrict__ Whh_d,
    unsigned short* __restrict__ WdTm, unsigned short* __restrict__ WdecTm) {
  int idx = blockIdx.x * blockDim.x + threadIdx.x;
  if (idx < 32768) {
    int j = idx & 7, l = (idx >> 3) & 63, t = idx >> 9;
    int nt = t & 7, ks = t >> 3;
    int k = ks * 32 + (l >> 4) * 8 + j;
    int n = nt * 16 + (l & 15);
    WdTm[idx] = f2bfu(W_d[n * 256 + k]);
    return;
  }
  int i2 = idx - 32768;
  if (i2 < 147456) {
    int j = i2 & 7, l = (i2 >> 3) & 63, t = i2 >> 9;
    int ks = t % 9, tile = t / 9;
    int q = tile & 3, is = tile >> 2;
    int k = ks * 32 + (l >> 4) * 8 + j;
    int g = q * 128 + is * 16 + (l & 15);
    float v;
    if (k < 128)      v = Whh_d[g * 128 + k];
    else if (k < 256) v = Wih_d[g * 137 + 9 + (k - 128)];
    else if (k < 265) v = Wih_d[g * 137 + (k - 256)];
    else              v = 0.f;
    WdecTm[i2] = f2bfu(v);
  }
}

// ---------------------------------------------------------------- prep encoder MFMA weights + VdTm
__global__ void prep_enc_mfma_kernel(const float* __restrict__ W_e,
    const float* __restrict__ Wih_e, const float* __restrict__ Whh_e,
    const float* __restrict__ V_d,
    unsigned short* __restrict__ WeTm, unsigned short* __restrict__ WencTm,
    unsigned short* __restrict__ VdTm) {
  int idx = blockIdx.x * blockDim.x + threadIdx.x;
  if (idx < 16384) {
    int j = idx & 7, l = (idx >> 3) & 63, tile = idx >> 9;
    int nt = tile & 3, ks = tile >> 2;
    int k = ks * 32 + (l >> 4) * 8 + j;
    int n = nt * 16 + (l & 15);
    WeTm[idx] = f2bfu(W_e[n * 256 + k]);
    return;
  }
  int i2 = idx - 16384;
  if (i2 < 81920) {
    int j = i2 & 7, l = (i2 >> 3) & 63, tile = i2 >> 9;
    int ks = tile % 5, tq = tile / 5;
    int q = tq & 3, is = tq >> 2;
    int kk = (l >> 4) * 8 + j;
    int g = q * 128 + is * 16 + (l & 15);
    float v;
    if (ks < 4) v = Whh_e[g * 128 + ks * 32 + kk];
    else        v = (kk < 9) ? Wih_e[g * 9 + kk] : 0.f;
    WencTm[i2] = f2bfu(v);
    return;
  }
  int i3 = i2 - 81920;
  if (i3 < 16384) {
    int j = i3 & 7, l = (i3 >> 3) & 63, tile = i3 >> 9;
    int nt = tile & 7, ks = tile >> 3;
    int i = ks * 32 + (l >> 4) * 8 + j;
    int n = nt * 16 + (l & 15);
    VdTm[i3] = f2bfu(V_d[n * 128 + i]);
  }
}

// ---------------------------------------------------------------- encoder (R9-exact: MFMA, 16 batches, 512 thr)
__global__ __launch_bounds__(512, 1) void encoder_mfma_kernel(
    const float* __restrict__ x_in, const float* __restrict__ ws,
    const float* __restrict__ v_e_g,
    const unsigned short* __restrict__ WeTm, const unsigned short* __restrict__ WencTm,
    __hip_bfloat16* __restrict__ EH,
    unsigned short* __restrict__ dG, float* __restrict__ cG) {
  __shared__ unsigned short hA[2][16 * 296];  // [h | c | xs | zeros]
  __shared__ float cF[16 * 132];
  __shared__ float ahL[16 * 64];
  __shared__ unsigned short aiL[16 * 576];    // bf16
  __shared__ unsigned short xbL[16 * 576];    // bf16

  const int tid = threadIdx.x;
  const int b0 = blockIdx.x * 16;
  const int l = tid & 63, w = tid >> 6;
  const int quad = l >> 4, l15 = l & 15;

  for (int i = tid; i < 16 * 576; i += 512) {
    int m = i / 576, r = i % 576;
    xbL[i] = f2bfu(x_in[(size_t)(b0 + m) * 576 + r]);
  }
  for (int i = tid; i < 2 * 16 * 296; i += 512) ((unsigned short*)hA)[i] = 0;
  for (int i = tid; i < 16 * 132; i += 512) cF[i] = 0.f;
  __syncthreads();

  {
    const float* __restrict__ VeT = ws + OFF_VET;
    for (int i = tid; i < 16 * 576; i += 512) {
      int t = i & 63, dd = (i >> 6) % 9, m = i / 576;
      float acc = 0.f;
      for (int s = 0; s < 64; ++s) acc += bfu2f(xbL[m * 576 + s * 9 + dd]) * VeT[s * 64 + t];
      aiL[m * 576 + dd * 64 + t] = f2bfu(acc);
    }
  }
  const float ve_r = v_e_g[l];
  const int ig = w * 16 + l15;
  float bbq[4];
  #pragma unroll
  for (int q = 0; q < 4; ++q) bbq[q] = ws[OFF_BENC + q * 128 + ig];
  __syncthreads();

  for (int t = 0; t < S_; ++t) {
    unsigned short* bufC = hA[t & 1];
    unsigned short* bufN = hA[(t + 1) & 1];
    if (w < 4) {
      f32x4 acc = {0.f, 0.f, 0.f, 0.f};
      #pragma unroll
      for (int ks = 0; ks < 8; ++ks) {
        uint4 au = *(const uint4*)&bufC[l15 * 296 + ks * 32 + quad * 8];
        uint4 bu = *(const uint4*)(WeTm + (size_t)((ks * 4 + w) * 64 + l) * 8);
        acc = __builtin_amdgcn_mfma_f32_16x16x32_bf16(
            __builtin_bit_cast(bf16x8, au), __builtin_bit_cast(bf16x8, bu), acc, 0, 0, 0);
      }
      #pragma unroll
      for (int r = 0; r < 4; ++r)
        ahL[(quad * 4 + r) * 64 + w * 16 + l15] = acc[r];
    }
    __syncthreads();
    {
      const int m0 = 2 * w, m1 = 2 * w + 1;
      float a0 = ahL[m0 * 64 + l], a1 = ahL[m1 * 64 + l];
      float e0k = -1e30f, e1k = -1e30f;
      #pragma unroll
      for (int dd = 0; dd < 9; ++dd) {
        float t0 = fast_tanh(a0 + bfu2f(aiL[m0 * 576 + dd * 64 + l])) * ve_r;
        float t1 = fast_tanh(a1 + bfu2f(aiL[m1 * 576 + dd * 64 + l])) * ve_r;
        #pragma unroll
        for (int off = 32; off; off >>= 1) {
          t0 += __shfl_xor(t0, off, 64);
          t1 += __shfl_xor(t1, off, 64);
        }
        if (l == dd) { e0k = t0; e1k = t1; }
      }
      float mx0 = e0k, mx1 = e1k;
      #pragma unroll
      for (int off = 8; off; off >>= 1) {
        mx0 = fmaxf(mx0, __shfl_xor(mx0, off, 64));
        mx1 = fmaxf(mx1, __shfl_xor(mx1, off, 64));
      }
      float ex0 = (l < 9) ? __expf(e0k - mx0) : 0.f;
      float ex1 = (l < 9) ? __expf(e1k - mx1) : 0.f;
      float s0 = ex0, s1 = ex1;
      #pragma unroll
      for (int off = 8; off; off >>= 1) {
        s0 += __shfl_xor(s0, off, 64);
        s1 += __shfl_xor(s1, off, 64);
      }
      if (l < 9) {
        bufC[m0 * 296 + 256 + l] = f2bfu(__fdividef(ex0, s0) * bfu2f(xbL[m0 * 576 + t * 9 + l]));
        bufC[m1 * 296 + 256 + l] = f2bfu(__fdividef(ex1, s1) * bfu2f(xbL[m1 * 576 + t * 9 + l]));
      }
    }
    __syncthreads();
    {
      uint4 af[5];
      #pragma unroll
      for (int ks = 0; ks < 4; ++ks)
        af[ks] = *(const uint4*)&bufC[l15 * 296 + ks * 32 + quad * 8];
      af[4] = *(const uint4*)&bufC[l15 * 296 + 256 + quad * 8];
      f32x4 g4[4];
      #pragma unroll
      for (int q = 0; q < 4; ++q) {
        f32x4 acc = {0.f, 0.f, 0.f, 0.f};
        #pragma unroll
        for (int ks = 0; ks < 5; ++ks) {
          uint4 bu = *(const uint4*)(WencTm + (size_t)(((w * 4 + q) * 5 + ks) * 64 + l) * 8);
          acc = __builtin_amdgcn_mfma_f32_16x16x32_bf16(
              __builtin_bit_cast(bf16x8, af[ks]), __builtin_bit_cast(bf16x8, bu), acc, 0, 0, 0);
        }
        g4[q] = acc;
      }
      #pragma unroll
      for (int r = 0; r < 4; ++r) {
        int m = quad * 4 + r;
        float gi = g4[0][r] + bbq[0];
        float gf = g4[1][r] + bbq[1];
        float gg = g4[2][r] + bbq[2];
        float go = g4[3][r] + bbq[3];
        float co = cF[m * 132 + ig];
        float cn = sigf(gf) * co + sigf(gi) * fast_tanh(gg);
        float hn = sigf(go) * fast_tanh(cn);
        cF[m * 132 + ig] = cn;
        bufN[m * 296 + ig] = f2bfu(hn);
        bufN[m * 296 + 128 + ig] = f2bfu(cn);
        EH[((size_t)(b0 + m) * S_ + t) * H_ + ig] = __float2bfloat16(hn);
      }
    }
    __syncthreads();
  }
  for (int i = tid; i < 16 * 128; i += 512) {
    int m = i >> 7, ii = i & 127;
    dG[(size_t)(b0 + m) * 128 + ii] = hA[0][m * 296 + ii];
    cG[(size_t)(b0 + m) * 128 + ii] = cF[m * 132 + ii];
  }
}

// ---------------------------------------------------------------- attn_encoder^T via MFMA -> fp8
__global__ __launch_bounds__(256) void attnenc_mfma_kernel(
    const unsigned short* __restrict__ EH, const unsigned short* __restrict__ VdTm,
    unsigned char* __restrict__ AETf8, unsigned char* __restrict__ EHf8) {
  const int tid = threadIdx.x;
  const int b = blockIdx.x * 4 + (tid >> 6);
  const int l = tid & 63;
  const int quad = l >> 4, l15 = l & 15;

  const unsigned short* ehb = EH + (size_t)b * 8192;
  uint4 A[4][4];
  #pragma unroll
  for (int st = 0; st < 4; ++st)
    #pragma unroll
    for (int ks = 0; ks < 4; ++ks)
      A[st][ks] = *(const uint4*)(ehb + (st * 16 + l15) * 128 + ks * 32 + quad * 8);

  {
    unsigned char* e8b = EHf8 + (size_t)b * 8192;
    #pragma unroll
    for (int st = 0; st < 4; ++st)
      #pragma unroll
      for (int ks = 0; ks < 4; ++ks) {
        uint4 a = A[st][ks];
        uint2 pk;
        pk.x = pack4_f8(bf_lo(a.x), bf_hi(a.x), bf_lo(a.y), bf_hi(a.y));
        pk.y = pack4_f8(bf_lo(a.z), bf_hi(a.z), bf_lo(a.w), bf_hi(a.w));
        *(uint2*)(e8b + (st * 16 + l15) * 128 + ks * 32 + quad * 8) = pk;
      }
  }

  unsigned char* outb = AETf8 + (size_t)b * 8192;
  const int k = l15;
  #pragma unroll
  for (int nt = 0; nt < 8; ++nt) {
    uint4 Bf[4];
    #pragma unroll
    for (int ks = 0; ks < 4; ++ks)
      Bf[ks] = *(const uint4*)(VdTm + (size_t)((ks * 8 + nt) * 64 + l) * 8);
    int kg = nt * 16 + k;
    int kb = kg >> 3, k7 = kg & 7;
    #pragma unroll
    for (int st = 0; st < 4; ++st) {
      f32x4 acc = {0.f, 0.f, 0.f, 0.f};
      #pragma unroll
      for (int ks = 0; ks < 4; ++ks)
        acc = __builtin_amdgcn_mfma_f32_16x16x32_bf16(
            __builtin_bit_cast(bf16x8, A[st][ks]), __builtin_bit_cast(bf16x8, Bf[ks]), acc, 0, 0, 0);
      #pragma unroll
      for (int r = 0; r < 4; ++r) {
        int s = st * 16 + quad * 4 + r;
        outb[kb * 512 + s * 8 + k7] = f2f8(acc[r]);
      }
    }
  }
}

// ---------------------------------------------------------------- decoder init: pvsG + ad0 (MFMA)
__global__ __launch_bounds__(256) void init_dec_kernel(
    const float* __restrict__ x_in,
    const unsigned short* __restrict__ dG, const float* __restrict__ cG,
    const unsigned short* __restrict__ WdTm,
    const float* __restrict__ smean_g, const float* __restrict__ sstd_g,
    const float* __restrict__ pmean_g,
    unsigned short* __restrict__ adG, float* __restrict__ pvsG) {
  __shared__ unsigned short dcB[16 * 264];
  const int tid = threadIdx.x;
  const int b0 = blockIdx.x * 16;
  const int l = tid & 63, w = tid >> 6;
  const int quad = l >> 4, l15 = l & 15;

  {
    int m = tid >> 4, i0 = (tid & 15) * 8;
    *(uint4*)&dcB[m * 264 + i0] = *(const uint4*)(dG + (size_t)(b0 + m) * 128 + i0);
    float4 c0 = *(const float4*)(cG + (size_t)(b0 + m) * 128 + i0);
    float4 c1 = *(const float4*)(cG + (size_t)(b0 + m) * 128 + i0 + 4);
    uint4 pk;
    pk.x = pack_bf(c0.x, c0.y); pk.y = pack_bf(c0.z, c0.w);
    pk.z = pack_bf(c1.x, c1.y); pk.w = pack_bf(c1.z, c1.w);
    *(uint4*)&dcB[m * 264 + 128 + i0] = pk;
  }
  if (tid < 48) {
    int m = tid / 3, jj = tid % 3;
    const float* xi = x_in + (size_t)(b0 + m) * 576;
    float sm = smean_g[jj], ss = sstd_g[jj], pm = pmean_g[jj];
    float v  = xi[63 * 9 + 3 + jj] * ss + sm;
    float pv = xi[62 * 9 + 3 + jj] * ss + sm;
    float* P = pvsG + (size_t)(b0 + m) * 12;
    P[jj] = xi[63 * 9 + jj] + pm;
    P[3 + jj] = v;
    P[6 + jj] = (v - pv) / DT_;
  }
  __syncthreads();
  #pragma unroll
  for (int t = 0; t < 2; ++t) {
    const int nt = w + 4 * t;
    f32x4 acc = {0.f, 0.f, 0.f, 0.f};
    #pragma unroll
    for (int ks = 0; ks < 8; ++ks) {
      uint4 au = *(const uint4*)&dcB[l15 * 264 + ks * 32 + quad * 8];
      uint4 bu = *(const uint4*)(WdTm + (size_t)((ks * 8 + nt) * 64 + l) * 8);
      acc = __builtin_amdgcn_mfma_f32_16x16x32_bf16(
          __builtin_bit_cast(bf16x8, au), __builtin_bit_cast(bf16x8, bu), acc, 0, 0, 0);
    }
    int n = nt * 16 + l15;
    #pragma unroll
    for (int r = 0; r < 4; ++r)
      adG[(size_t)(b0 + quad * 4 + r) * 128 + n] = f2bfu(acc[r]);
  }
}

// ---------------------------------------------------------------- fused decoder step
// 256 blocks x 512 thr, 16 batches/block. Wave w owns batches {2w, 2w+1} for score+ctx
// (full k per wave -> no cross-wave combine; |e|<=sum|v_d|~5 -> max-subtract dropped, exact).
// Then gates/LSTM/next-ad phases identical to the proven gemm_step.
__global__ __launch_bounds__(512, 2) void dec_step_kernel(
    const float* __restrict__ ws,
    const unsigned char* __restrict__ AETf8, const unsigned char* __restrict__ EHf8,
    const unsigned short* __restrict__ dG_in, float* __restrict__ cG,
    const unsigned short* __restrict__ WdTm, const unsigned short* __restrict__ WdecTm,
    unsigned short* __restrict__ dG_out, unsigned short* __restrict__ adG,
    float* __restrict__ pvsG, const float* __restrict__ v_d_g,
    const float* __restrict__ b_out_g, const float* __restrict__ smean_g,
    const float* __restrict__ sstd_g, const float* __restrict__ pmean_g,
    float* __restrict__ out, int hz) {
  __shared__ unsigned short adL[16 * 128];
  __shared__ float vdL[128];
  __shared__ float bet[16 * 64];
  __shared__ unsigned short gA[16 * 296];
  __shared__ unsigned short dcB[16 * 264];
  __shared__ float pd[16 * 3 * 8];
  __shared__ float pc[16 * 3 * 4];

  const int tid = threadIdx.x;
  const int b0 = blockIdx.x * 16;
  const int l = tid & 63, w = tid >> 6;
  const int quad = l >> 4, l15 = l & 15;

  // ---- stage
  if (tid < 256) {
    int m = tid >> 4, i0 = (tid & 15) * 8;
    *(uint4*)&gA[m * 296 + i0] = *(const uint4*)(dG_in + (size_t)(b0 + m) * 128 + i0);
  } else {
    int t = tid - 256;
    int m = t >> 4, i0 = (t & 15) * 8;
    *(uint4*)&adL[m * 128 + i0] = *(const uint4*)(adG + (size_t)(b0 + m) * 128 + i0);
  }
  if (tid < 128) vdL[tid] = v_d_g[tid];
  if (tid < 496) { int mm = tid / 31, r = tid % 31; gA[mm * 296 + 265 + r] = 0; }
  if (tid < 48) {
    int m = tid / 3, jj = tid % 3;
    const float* P = pvsG + (size_t)(b0 + m) * 12;
    float sm = smean_g[jj], ss = sstd_g[jj], pm = pmean_g[jj];
    gA[m * 296 + 256 + jj]     = f2bfu(P[jj] - pm);
    gA[m * 296 + 256 + 3 + jj] = f2bfu((P[3 + jj] - sm) / ss);
    gA[m * 296 + 256 + 6 + jj] = f2bfu(P[6 + jj] / ss);
  }
  __syncthreads();

  // ---- score + softmax (lane = s, full k) for batches 2w, 2w+1
  #pragma unroll
  for (int u = 0; u < 2; ++u) {
    const int mi = 2 * w + u;
    const unsigned char* aet = AETf8 + (size_t)(b0 + mi) * 8192;
    const unsigned short* adp = adL + mi * 128;
    float e = 0.f;
    #pragma unroll
    for (int kb = 0; kb < 16; ++kb) {
      uint2 av = *(const uint2*)(aet + kb * 512 + l * 8);
      uint4 ad8 = *(const uint4*)(adp + kb * 8);
      float4 v0 = *(const float4*)&vdL[kb * 8];
      float4 v1 = *(const float4*)&vdL[kb * 8 + 4];
      e += fast_tanh(bf_lo(ad8.x) + f8tof(av.x))       * v0.x;
      e += fast_tanh(bf_hi(ad8.x) + f8tof(av.x >> 8))  * v0.y;
      e += fast_tanh(bf_lo(ad8.y) + f8tof(av.x >> 16)) * v0.z;
      e += fast_tanh(bf_hi(ad8.y) + f8tof(av.x >> 24)) * v0.w;
      e += fast_tanh(bf_lo(ad8.z) + f8tof(av.y))       * v1.x;
      e += fast_tanh(bf_hi(ad8.z) + f8tof(av.y >> 8))  * v1.y;
      e += fast_tanh(bf_lo(ad8.w) + f8tof(av.y >> 16)) * v1.z;
      e += fast_tanh(bf_hi(ad8.w) + f8tof(av.y >> 24)) * v1.w;
    }
    // |e| <= sum|v_d| (~5): exp safe without max-subtraction
    float ex = __expf(e);
    float ss = ex;
    #pragma unroll
    for (int off = 32; off; off >>= 1) ss += __shfl_xor(ss, off, 64);
    bet[mi * 64 + l] = __fdividef(ex, ss);
  }
  // ---- context (same wave owns same batches -> no barrier needed)
  #pragma unroll
  for (int u = 0; u < 2; ++u) {
    const int mi = 2 * w + u;
    const unsigned char* base = EHf8 + (size_t)(b0 + mi) * 8192;
    float a[8];
    #pragma unroll
    for (int r = 0; r < 8; ++r) a[r] = 0.f;
    #pragma unroll
    for (int it = 0; it < 16; ++it) {
      int sl = it * 4 + quad;
      uint2 ev = *(const uint2*)(base + sl * 128 + l15 * 8);
      float bt = bet[mi * 64 + sl];
      a[0] += bt * f8tof(ev.x);       a[1] += bt * f8tof(ev.x >> 8);
      a[2] += bt * f8tof(ev.x >> 16); a[3] += bt * f8tof(ev.x >> 24);
      a[4] += bt * f8tof(ev.y);       a[5] += bt * f8tof(ev.y >> 8);
      a[6] += bt * f8tof(ev.y >> 16); a[7] += bt * f8tof(ev.y >> 24);
    }
    #pragma unroll
    for (int r = 0; r < 8; ++r) {
      a[r] += __shfl_xor(a[r], 16, 64);
      a[r] += __shfl_xor(a[r], 32, 64);
    }
    if (quad == 0) {
      uint4 pk;
      pk.x = pack_bf(a[0], a[1]); pk.y = pack_bf(a[2], a[3]);
      pk.z = pack_bf(a[4], a[5]); pk.w = pack_bf(a[6], a[7]);
      *(uint4*)&gA[mi * 296 + 128 + l15 * 8] = pk;
    }
  }
  __syncthreads();

  // ---- gates (gate-permuted MFMA) + in-register LSTM. wave w -> i-slice w.
  {
    uint4 af[9];
    #pragma unroll
    for (int ks = 0; ks < 9; ++ks)
      af[ks] = *(const uint4*)&gA[l15 * 296 + ks * 32 + quad * 8];
    const int is = w, i = is * 16 + l15;
    float bb[4], wd[3];
    #pragma unroll
    for (int q = 0; q < 4; ++q) bb[q] = ws[OFF_BDEC + q * 128 + i];
    #pragma unroll
    for (int jj = 0; jj < 3; ++jj) wd[jj] = ws[OFF_WOUTT + i * 3 + jj];
    f32x4 g4[4];
    #pragma unroll
    for (int q = 0; q < 4; ++q) {
      f32x4 acc = {0.f, 0.f, 0.f, 0.f};
      #pragma unroll
      for (int ks = 0; ks < 9; ++ks) {
        uint4 bu = *(const uint4*)(WdecTm + (size_t)(((is * 4 + q) * 9 + ks) * 64 + l) * 8);
        acc = __builtin_amdgcn_mfma_f32_16x16x32_bf16(
            __builtin_bit_cast(bf16x8, af[ks]), __builtin_bit_cast(bf16x8, bu), acc, 0, 0, 0);
      }
      g4[q] = acc;
    }
    float pr[4][3];
    #pragma unroll
    for (int r = 0; r < 4; ++r) {
      int m = quad * 4 + r;
      float gi = g4[0][r] + bb[0];
      float gf = g4[1][r] + bb[1];
      float gg = g4[2][r] + bb[2];
      float go = g4[3][r] + bb[3];
      float co = cG[(size_t)(b0 + m) * 128 + i];
      float cn = sigf(gf) * co + sigf(gi) * fast_tanh(gg);
      float hn = sigf(go) * fast_tanh(cn);
      cG[(size_t)(b0 + m) * 128 + i] = cn;
      unsigned short hb = f2bfu(hn);
      dG_out[(size_t)(b0 + m) * 128 + i] = hb;
      dcB[m * 264 + i] = hb;
      dcB[m * 264 + 128 + i] = f2bfu(cn);
      pr[r][0] = hn * wd[0]; pr[r][1] = hn * wd[1]; pr[r][2] = hn * wd[2];
    }
    #pragma unroll
    for (int r = 0; r < 4; ++r)
      #pragma unroll
      for (int jj = 0; jj < 3; ++jj) {
        float v = pr[r][jj];
        #pragma unroll
        for (int off = 8; off; off >>= 1) v += __shfl_xor(v, off, 64);
        pr[r][jj] = v;
      }
    if (l15 == 0) {
      #pragma unroll
      for (int r = 0; r < 4; ++r)
        #pragma unroll
        for (int jj = 0; jj < 3; ++jj)
          pd[((quad * 4 + r) * 3 + jj) * 8 + is] = pr[r][jj];
    }
  }
  __syncthreads();

  // ---- next-step attn_dec MFMA + ctx out-partials
  {
    const int nt = w;
    f32x4 acc = {0.f, 0.f, 0.f, 0.f};
    #pragma unroll
    for (int ks = 0; ks < 8; ++ks) {
      uint4 au = *(const uint4*)&dcB[l15 * 264 + ks * 32 + quad * 8];
      uint4 bu = *(const uint4*)(WdTm + (size_t)((ks * 8 + nt) * 64 + l) * 8);
      acc = __builtin_amdgcn_mfma_f32_16x16x32_bf16(
          __builtin_bit_cast(bf16x8, au), __builtin_bit_cast(bf16x8, bu), acc, 0, 0, 0);
    }
    int n = nt * 16 + l15;
    #pragma unroll
    for (int r = 0; r < 4; ++r) {
      int m = quad * 4 + r;
      adG[(size_t)(b0 + m) * 128 + n] = f2bfu(acc[r]);
    }
  }
  if (tid < 192) {
    int m = tid / 12, jj = (tid % 12) / 4, part = tid % 4;
    int k0 = part * 32;
    float acc = 0.f;
    for (int k = k0; k < k0 + 32; ++k) {
      __hip_bfloat16 hv = *(__hip_bfloat16*)&gA[m * 296 + 128 + k];
      acc += __bfloat162float(hv) * ws[OFF_WOUTT + 384 + k * 3 + jj];
    }
    pc[(m * 3 + jj) * 4 + part] = acc;
  }
  __syncthreads();

  // ---- Verlet + output
  if (tid < 48) {
    int m = tid / 3, jj = tid % 3;
    float s = b_out_g[jj];
    #pragma unroll
    for (int p = 0; p < 4; ++p) s += pc[(m * 3 + jj) * 4 + p];
    #pragma unroll
    for (int is = 0; is < 8; ++is) s += pd[(m * 3 + jj) * 8 + is];
    float pacc = s * sstd_g[jj];
    float* P = pvsG + (size_t)(b0 + m) * 12;
    float pos = P[jj], vel = P[3 + jj], acc = P[6 + jj];
    float ppred = pos + vel * DT_ + 0.5f * acc * DT_ * DT_;
    float vnew  = vel + 0.5f * (acc + pacc) * DT_;
    size_t ob = ((size_t)(b0 + m) * HZ_ + hz) * 9;
    out[ob + jj] = ppred; out[ob + 3 + jj] = vnew; out[ob + 6 + jj] = pacc;
    P[jj] = ppred; P[3 + jj] = vnew; P[6 + jj] = pacc;
  }
}

// ---------------------------------------------------------------- launch
extern "C" void kernel_launch(void* const* d_in, const int* in_sizes, int n_in,
                              void* d_out, int out_size, void* d_ws, size_t ws_size,
                              hipStream_t stream) {
  (void)in_sizes; (void)n_in; (void)out_size; (void)ws_size;
  const float* x      = (const float*)d_in[0];
  const float* Wih_e  = (const float*)d_in[1];
  const float* Whh_e  = (const float*)d_in[2];
  const float* bih_e  = (const float*)d_in[3];
  const float* bhh_e  = (const float*)d_in[4];
  const float* W_e    = (const float*)d_in[5];
  const float* V_e    = (const float*)d_in[6];
  const float* v_e    = (const float*)d_in[7];
  const float* W_d    = (const float*)d_in[8];
  const float* V_d    = (const float*)d_in[9];
  const float* v_d    = (const float*)d_in[10];
  const float* Wih_d  = (const float*)d_in[11];
  const float* Whh_d  = (const float*)d_in[12];
  const float* bih_d  = (const float*)d_in[13];
  const float* bhh_d  = (const float*)d_in[14];
  const float* W_out  = (const float*)d_in[15];
  const float* b_out  = (const float*)d_in[16];
  const float* smean  = (const float*)d_in[17];
  const float* sstd   = (const float*)d_in[18];
  const float* pmean  = (const float*)d_in[19];

  float* ws = (float*)d_ws;
  float* pvsG = ws;                                           // over dead encoder tables
  unsigned short* WeTm   = (unsigned short*)(ws + OFF_WET);
  unsigned short* WencTm = (unsigned short*)(ws + OFF_WENCT);
  unsigned short* WdTm   = (unsigned short*)(ws + OFF_WDT);
  unsigned short* WdecTm = (unsigned short*)(ws + OFF_WDECT);
  unsigned short* VdTm   = (unsigned short*)(ws + OFF_VDT);
  unsigned short* dG     = (unsigned short*)(ws + OFF_DECD);
  float* cG = ws + OFF_DECC;
  unsigned short* ub  = (unsigned short*)(ws + F32_TOTAL);
  unsigned short* EH  = ub;
  unsigned char*  AETf8 = (unsigned char*)(ub + 33554432);
  unsigned char*  EHf8  = AETf8 + (size_t)B_ * 8192;
  unsigned short* adG = ub + 67108864;
  float* out = (float*)d_out;

  prep_kernel<<<(PREP_N + 255) / 256, 256, 0, stream>>>(
      Wih_e, Whh_e, bih_e, bhh_e, W_e, V_e, W_d, V_d,
      Wih_d, Whh_d, bih_d, bhh_d, W_out, ws);
  prep_mfma_kernel<<<(32768 + 147456 + 255) / 256, 256, 0, stream>>>(
      W_d, Wih_d, Whh_d, WdTm, WdecTm);
  prep_enc_mfma_kernel<<<(16384 + 81920 + 16384 + 255) / 256, 256, 0, stream>>>(
      W_e, Wih_e, Whh_e, V_d, WeTm, WencTm, VdTm);
  encoder_mfma_kernel<<<B_ / 16, 512, 0, stream>>>(
      x, ws, v_e, WeTm, WencTm, (__hip_bfloat16*)EH, dG, cG);
  attnenc_mfma_kernel<<<B_ / 4, 256, 0, stream>>>(EH, VdTm, AETf8, EHf8);
  init_dec_kernel<<<B_ / 16, 256, 0, stream>>>(
      x, dG, cG, WdTm, smean, sstd, pmean, adG, pvsG);
  for (int hz = 0; hz < HZ_; ++hz) {
    dec_step_kernel<<<B_ / 16, 512, 0, stream>>>(
        ws, AETf8, EHf8, dG, cG, WdTm, WdecTm, dG, adG, pvsG,
        v_d, b_out, smean, sstd, pmean, out, hz);
  }
}

// Round 12
// 1701.876 us; speedup vs baseline: 1.1389x; 1.1389x over previous
//
#include <hip/hip_runtime.h>
#include <hip/hip_bf16.h>
#include <hip/hip_fp8.h>

// Problem constants
#define B_   4096
#define S_   64
#define D_   9
#define H_   128
#define HZ_  32
#define DT_  0.1f

// f32 region layout (float offsets). Regions overlap in TIME, never within a kernel.
#define OFF_WET    0          // slot hosts WeTm  (bf16, 16384 ush) [encoder only]
#define OFF_VET    16384      // 4096 f32 V_e^T   [encoder only]
#define OFF_WENCT  20480      // slot hosts WencTm (bf16, 81920 ush) [encoder only]
#define OFF_BENC   90624      // 512   [encoder only]
#define OFF_WDT    91136      // slot hosts WdTm (bf16, 32768 ush)
#define OFF_WDECT  123904     // slot hosts WdecTm (bf16, 147456 ush)
#define OFF_BDEC   259584     // 512   (live, gemm)
#define OFF_WOUTT  260096     // 768   (live, gemm)
#define OFF_VDT    260864     // slot hosts VdTm (bf16, 16384 ush) [attnenc MFMA B-frags]
#define OFF_DECD   277248     // slot hosts dG (524288 ush) + ctxG (524288 ush)
#define OFF_DECC   801536     // 524288 : live c-state f32 (cG)
#define F32_TOTAL  1325824
#define PREP_N     277248

// ushort region after f32 region: EH bf16 (33554432 ush) | AETf8 + EHf8 (33.5M bytes each) | adG

typedef __bf16 bf16x8 __attribute__((ext_vector_type(8)));
typedef float  f32x4  __attribute__((ext_vector_type(4)));

__device__ __forceinline__ float fast_tanh(float x) {
    float e = __expf(2.0f * x);
    return 1.0f - __fdividef(2.0f, e + 1.0f);
}
__device__ __forceinline__ float sigf(float x) {
    return __fdividef(1.0f, 1.0f + __expf(-x));
}
__device__ __forceinline__ float bf_lo(unsigned int u) { return __uint_as_float(u << 16); }
__device__ __forceinline__ float bf_hi(unsigned int u) { return __uint_as_float(u & 0xffff0000u); }
__device__ __forceinline__ float bfu2f(unsigned short u) { return __uint_as_float((unsigned int)u << 16); }
__device__ __forceinline__ unsigned short f2bfu(float f) {
    __hip_bfloat16 b = __float2bfloat16(f);
    return *(unsigned short*)&b;
}
__device__ __forceinline__ unsigned int pack_bf(float lo, float hi) {
    return (unsigned int)f2bfu(lo) | ((unsigned int)f2bfu(hi) << 16);
}
__device__ __forceinline__ float f8tof(unsigned int byte) {
    __hip_fp8_e4m3 t; t.__x = (unsigned char)byte; return (float)t;
}
__device__ __forceinline__ unsigned char f2f8(float f) {
    __hip_fp8_e4m3 q(f); return q.__x;
}
__device__ __forceinline__ unsigned int pack4_f8(float a, float b, float c, float d) {
    return (unsigned int)f2f8(a) | ((unsigned int)f2f8(b) << 8) |
           ((unsigned int)f2f8(c) << 16) | ((unsigned int)f2f8(d) << 24);
}

// ---------------------------------------------------------------- prep (f32 tables)
__global__ void prep_kernel(const float* __restrict__ Wih_e, const float* __restrict__ Whh_e,
    const float* __restrict__ bih_e, const float* __restrict__ bhh_e,
    const float* __restrict__ W_e, const float* __restrict__ V_e,
    const float* __restrict__ W_d, const float* __restrict__ V_d,
    const float* __restrict__ Wih_d, const float* __restrict__ Whh_d,
    const float* __restrict__ bih_d, const float* __restrict__ bhh_d,
    const float* __restrict__ W_out, float* __restrict__ ws) {
  for (int idx = blockIdx.x * blockDim.x + threadIdx.x; idx < PREP_N;
       idx += gridDim.x * blockDim.x) {
    int i = idx;
    if (i < 16384) { continue; }
    i -= 16384;
    if (i < 4096) { int s = i >> 6, t = i & 63; ws[OFF_VET + i] = V_e[t * 64 + s]; continue; }
    i -= 4096;
    if (i < 70144) { continue; }
    i -= 70144;
    if (i < 512) { ws[OFF_BENC + i] = bih_e[i] + bhh_e[i]; continue; }
    i -= 512;
    if (i < 32768) { continue; }
    i -= 32768;
    if (i < 135680) { continue; }
    i -= 135680;
    if (i < 512) { ws[OFF_BDEC + i] = bih_d[i] + bhh_d[i]; continue; }
    i -= 512;
    if (i < 768) { int k = i / 3, j = i % 3; ws[OFF_WOUTT + i] = W_out[j * 256 + k]; continue; }
  }
}

// ---------------------------------------------------------------- prep decoder MFMA weights
__global__ void prep_mfma_kernel(const float* __restrict__ W_d,
    const float* __restrict__ Wih_d, const float* __restrict__ Whh_d,
    unsigned short* __restrict__ WdTm, unsigned short* __restrict__ WdecTm) {
  int idx = blockIdx.x * blockDim.x + threadIdx.x;
  if (idx < 32768) {
    int j = idx & 7, l = (idx >> 3) & 63, t = idx >> 9;
    int nt = t & 7, ks = t >> 3;
    int k = ks * 32 + (l >> 4) * 8 + j;
    int n = nt * 16 + (l & 15);
    WdTm[idx] = f2bfu(W_d[n * 256 + k]);
    return;
  }
  int i2 = idx - 32768;
  if (i2 < 147456) {
    int j = i2 & 7, l = (i2 >> 3) & 63, t = i2 >> 9;
    int ks = t % 9, tile = t / 9;
    int q = tile & 3, is = tile >> 2;
    int k = ks * 32 + (l >> 4) * 8 + j;
    int g = q * 128 + is * 16 + (l & 15);
    float v;
    if (k < 128)      v = Whh_d[g * 128 + k];
    else if (k < 256) v = Wih_d[g * 137 + 9 + (k - 128)];
    else if (k < 265) v = Wih_d[g * 137 + (k - 256)];
    else              v = 0.f;
    WdecTm[i2] = f2bfu(v);
  }
}

// ---------------------------------------------------------------- prep encoder MFMA weights + VdTm
__global__ void prep_enc_mfma_kernel(const float* __restrict__ W_e,
    const float* __restrict__ Wih_e, const float* __restrict__ Whh_e,
    const float* __restrict__ V_d,
    unsigned short* __restrict__ WeTm, unsigned short* __restrict__ WencTm,
    unsigned short* __restrict__ VdTm) {
  int idx = blockIdx.x * blockDim.x + threadIdx.x;
  if (idx < 16384) {
    int j = idx & 7, l = (idx >> 3) & 63, tile = idx >> 9;
    int nt = tile & 3, ks = tile >> 2;
    int k = ks * 32 + (l >> 4) * 8 + j;
    int n = nt * 16 + (l & 15);
    WeTm[idx] = f2bfu(W_e[n * 256 + k]);
    return;
  }
  int i2 = idx - 16384;
  if (i2 < 81920) {
    int j = i2 & 7, l = (i2 >> 3) & 63, tile = i2 >> 9;
    int ks = tile % 5, tq = tile / 5;
    int q = tq & 3, is = tq >> 2;
    int kk = (l >> 4) * 8 + j;
    int g = q * 128 + is * 16 + (l & 15);
    float v;
    if (ks < 4) v = Whh_e[g * 128 + ks * 32 + kk];
    else        v = (kk < 9) ? Wih_e[g * 9 + kk] : 0.f;
    WencTm[i2] = f2bfu(v);
    return;
  }
  int i3 = i2 - 81920;
  if (i3 < 16384) {
    int j = i3 & 7, l = (i3 >> 3) & 63, tile = i3 >> 9;
    int nt = tile & 7, ks = tile >> 3;
    int i = ks * 32 + (l >> 4) * 8 + j;
    int n = nt * 16 + (l & 15);
    VdTm[i3] = f2bfu(V_d[n * 128 + i]);
  }
}

// ---------------------------------------------------------------- encoder (R9-exact: MFMA, 16 batches, 512 thr)
__global__ __launch_bounds__(512, 1) void encoder_mfma_kernel(
    const float* __restrict__ x_in, const float* __restrict__ ws,
    const float* __restrict__ v_e_g,
    const unsigned short* __restrict__ WeTm, const unsigned short* __restrict__ WencTm,
    __hip_bfloat16* __restrict__ EH,
    unsigned short* __restrict__ dG, float* __restrict__ cG) {
  __shared__ unsigned short hA[2][16 * 296];  // [h | c | xs | zeros]
  __shared__ float cF[16 * 132];
  __shared__ float ahL[16 * 64];
  __shared__ unsigned short aiL[16 * 576];    // bf16
  __shared__ unsigned short xbL[16 * 576];    // bf16

  const int tid = threadIdx.x;
  const int b0 = blockIdx.x * 16;
  const int l = tid & 63, w = tid >> 6;
  const int quad = l >> 4, l15 = l & 15;

  for (int i = tid; i < 16 * 576; i += 512) {
    int m = i / 576, r = i % 576;
    xbL[i] = f2bfu(x_in[(size_t)(b0 + m) * 576 + r]);
  }
  for (int i = tid; i < 2 * 16 * 296; i += 512) ((unsigned short*)hA)[i] = 0;
  for (int i = tid; i < 16 * 132; i += 512) cF[i] = 0.f;
  __syncthreads();

  {
    const float* __restrict__ VeT = ws + OFF_VET;
    for (int i = tid; i < 16 * 576; i += 512) {
      int t = i & 63, dd = (i >> 6) % 9, m = i / 576;
      float acc = 0.f;
      for (int s = 0; s < 64; ++s) acc += bfu2f(xbL[m * 576 + s * 9 + dd]) * VeT[s * 64 + t];
      aiL[m * 576 + dd * 64 + t] = f2bfu(acc);
    }
  }
  const float ve_r = v_e_g[l];
  const int ig = w * 16 + l15;
  float bbq[4];
  #pragma unroll
  for (int q = 0; q < 4; ++q) bbq[q] = ws[OFF_BENC + q * 128 + ig];
  __syncthreads();

  for (int t = 0; t < S_; ++t) {
    unsigned short* bufC = hA[t & 1];
    unsigned short* bufN = hA[(t + 1) & 1];
    if (w < 4) {
      f32x4 acc = {0.f, 0.f, 0.f, 0.f};
      #pragma unroll
      for (int ks = 0; ks < 8; ++ks) {
        uint4 au = *(const uint4*)&bufC[l15 * 296 + ks * 32 + quad * 8];
        uint4 bu = *(const uint4*)(WeTm + (size_t)((ks * 4 + w) * 64 + l) * 8);
        acc = __builtin_amdgcn_mfma_f32_16x16x32_bf16(
            __builtin_bit_cast(bf16x8, au), __builtin_bit_cast(bf16x8, bu), acc, 0, 0, 0);
      }
      #pragma unroll
      for (int r = 0; r < 4; ++r)
        ahL[(quad * 4 + r) * 64 + w * 16 + l15] = acc[r];
    }
    __syncthreads();
    {
      const int m0 = 2 * w, m1 = 2 * w + 1;
      float a0 = ahL[m0 * 64 + l], a1 = ahL[m1 * 64 + l];
      float e0k = -1e30f, e1k = -1e30f;
      #pragma unroll
      for (int dd = 0; dd < 9; ++dd) {
        float t0 = fast_tanh(a0 + bfu2f(aiL[m0 * 576 + dd * 64 + l])) * ve_r;
        float t1 = fast_tanh(a1 + bfu2f(aiL[m1 * 576 + dd * 64 + l])) * ve_r;
        #pragma unroll
        for (int off = 32; off; off >>= 1) {
          t0 += __shfl_xor(t0, off, 64);
          t1 += __shfl_xor(t1, off, 64);
        }
        if (l == dd) { e0k = t0; e1k = t1; }
      }
      float mx0 = e0k, mx1 = e1k;
      #pragma unroll
      for (int off = 8; off; off >>= 1) {
        mx0 = fmaxf(mx0, __shfl_xor(mx0, off, 64));
        mx1 = fmaxf(mx1, __shfl_xor(mx1, off, 64));
      }
      float ex0 = (l < 9) ? __expf(e0k - mx0) : 0.f;
      float ex1 = (l < 9) ? __expf(e1k - mx1) : 0.f;
      float s0 = ex0, s1 = ex1;
      #pragma unroll
      for (int off = 8; off; off >>= 1) {
        s0 += __shfl_xor(s0, off, 64);
        s1 += __shfl_xor(s1, off, 64);
      }
      if (l < 9) {
        bufC[m0 * 296 + 256 + l] = f2bfu(__fdividef(ex0, s0) * bfu2f(xbL[m0 * 576 + t * 9 + l]));
        bufC[m1 * 296 + 256 + l] = f2bfu(__fdividef(ex1, s1) * bfu2f(xbL[m1 * 576 + t * 9 + l]));
      }
    }
    __syncthreads();
    {
      uint4 af[5];
      #pragma unroll
      for (int ks = 0; ks < 4; ++ks)
        af[ks] = *(const uint4*)&bufC[l15 * 296 + ks * 32 + quad * 8];
      af[4] = *(const uint4*)&bufC[l15 * 296 + 256 + quad * 8];
      f32x4 g4[4];
      #pragma unroll
      for (int q = 0; q < 4; ++q) {
        f32x4 acc = {0.f, 0.f, 0.f, 0.f};
        #pragma unroll
        for (int ks = 0; ks < 5; ++ks) {
          uint4 bu = *(const uint4*)(WencTm + (size_t)(((w * 4 + q) * 5 + ks) * 64 + l) * 8);
          acc = __builtin_amdgcn_mfma_f32_16x16x32_bf16(
              __builtin_bit_cast(bf16x8, af[ks]), __builtin_bit_cast(bf16x8, bu), acc, 0, 0, 0);
        }
        g4[q] = acc;
      }
      #pragma unroll
      for (int r = 0; r < 4; ++r) {
        int m = quad * 4 + r;
        float gi = g4[0][r] + bbq[0];
        float gf = g4[1][r] + bbq[1];
        float gg = g4[2][r] + bbq[2];
        float go = g4[3][r] + bbq[3];
        float co = cF[m * 132 + ig];
        float cn = sigf(gf) * co + sigf(gi) * fast_tanh(gg);
        float hn = sigf(go) * fast_tanh(cn);
        cF[m * 132 + ig] = cn;
        bufN[m * 296 + ig] = f2bfu(hn);
        bufN[m * 296 + 128 + ig] = f2bfu(cn);
        EH[((size_t)(b0 + m) * S_ + t) * H_ + ig] = __float2bfloat16(hn);
      }
    }
    __syncthreads();
  }
  for (int i = tid; i < 16 * 128; i += 512) {
    int m = i >> 7, ii = i & 127;
    dG[(size_t)(b0 + m) * 128 + ii] = hA[0][m * 296 + ii];
    cG[(size_t)(b0 + m) * 128 + ii] = cF[m * 132 + ii];
  }
}

// ---------------------------------------------------------------- attn_encoder^T via MFMA -> fp8
__global__ __launch_bounds__(256) void attnenc_mfma_kernel(
    const unsigned short* __restrict__ EH, const unsigned short* __restrict__ VdTm,
    unsigned char* __restrict__ AETf8, unsigned char* __restrict__ EHf8) {
  const int tid = threadIdx.x;
  const int b = blockIdx.x * 4 + (tid >> 6);
  const int l = tid & 63;
  const int quad = l >> 4, l15 = l & 15;

  const unsigned short* ehb = EH + (size_t)b * 8192;
  uint4 A[4][4];
  #pragma unroll
  for (int st = 0; st < 4; ++st)
    #pragma unroll
    for (int ks = 0; ks < 4; ++ks)
      A[st][ks] = *(const uint4*)(ehb + (st * 16 + l15) * 128 + ks * 32 + quad * 8);

  {
    unsigned char* e8b = EHf8 + (size_t)b * 8192;
    #pragma unroll
    for (int st = 0; st < 4; ++st)
      #pragma unroll
      for (int ks = 0; ks < 4; ++ks) {
        uint4 a = A[st][ks];
        uint2 pk;
        pk.x = pack4_f8(bf_lo(a.x), bf_hi(a.x), bf_lo(a.y), bf_hi(a.y));
        pk.y = pack4_f8(bf_lo(a.z), bf_hi(a.z), bf_lo(a.w), bf_hi(a.w));
        *(uint2*)(e8b + (st * 16 + l15) * 128 + ks * 32 + quad * 8) = pk;
      }
  }

  unsigned char* outb = AETf8 + (size_t)b * 8192;
  const int k = l15;
  #pragma unroll
  for (int nt = 0; nt < 8; ++nt) {
    uint4 Bf[4];
    #pragma unroll
    for (int ks = 0; ks < 4; ++ks)
      Bf[ks] = *(const uint4*)(VdTm + (size_t)((ks * 8 + nt) * 64 + l) * 8);
    int kg = nt * 16 + k;
    int kb = kg >> 3, k7 = kg & 7;
    #pragma unroll
    for (int st = 0; st < 4; ++st) {
      f32x4 acc = {0.f, 0.f, 0.f, 0.f};
      #pragma unroll
      for (int ks = 0; ks < 4; ++ks)
        acc = __builtin_amdgcn_mfma_f32_16x16x32_bf16(
            __builtin_bit_cast(bf16x8, A[st][ks]), __builtin_bit_cast(bf16x8, Bf[ks]), acc, 0, 0, 0);
      #pragma unroll
      for (int r = 0; r < 4; ++r) {
        int s = st * 16 + quad * 4 + r;
        outb[kb * 512 + s * 8 + k7] = f2f8(acc[r]);
      }
    }
  }
}

// ---------------------------------------------------------------- decoder init: pvsG + ad0 (MFMA)
__global__ __launch_bounds__(256) void init_dec_kernel(
    const float* __restrict__ x_in,
    const unsigned short* __restrict__ dG, const float* __restrict__ cG,
    const unsigned short* __restrict__ WdTm,
    const float* __restrict__ smean_g, const float* __restrict__ sstd_g,
    const float* __restrict__ pmean_g,
    unsigned short* __restrict__ adG, float* __restrict__ pvsG) {
  __shared__ unsigned short dcB[16 * 264];
  const int tid = threadIdx.x;
  const int b0 = blockIdx.x * 16;
  const int l = tid & 63, w = tid >> 6;
  const int quad = l >> 4, l15 = l & 15;

  {
    int m = tid >> 4, i0 = (tid & 15) * 8;
    *(uint4*)&dcB[m * 264 + i0] = *(const uint4*)(dG + (size_t)(b0 + m) * 128 + i0);
    float4 c0 = *(const float4*)(cG + (size_t)(b0 + m) * 128 + i0);
    float4 c1 = *(const float4*)(cG + (size_t)(b0 + m) * 128 + i0 + 4);
    uint4 pk;
    pk.x = pack_bf(c0.x, c0.y); pk.y = pack_bf(c0.z, c0.w);
    pk.z = pack_bf(c1.x, c1.y); pk.w = pack_bf(c1.z, c1.w);
    *(uint4*)&dcB[m * 264 + 128 + i0] = pk;
  }
  if (tid < 48) {
    int m = tid / 3, jj = tid % 3;
    const float* xi = x_in + (size_t)(b0 + m) * 576;
    float sm = smean_g[jj], ss = sstd_g[jj], pm = pmean_g[jj];
    float v  = xi[63 * 9 + 3 + jj] * ss + sm;
    float pv = xi[62 * 9 + 3 + jj] * ss + sm;
    float* P = pvsG + (size_t)(b0 + m) * 12;
    P[jj] = xi[63 * 9 + jj] + pm;
    P[3 + jj] = v;
    P[6 + jj] = (v - pv) / DT_;
  }
  __syncthreads();
  #pragma unroll
  for (int t = 0; t < 2; ++t) {
    const int nt = w + 4 * t;
    f32x4 acc = {0.f, 0.f, 0.f, 0.f};
    #pragma unroll
    for (int ks = 0; ks < 8; ++ks) {
      uint4 au = *(const uint4*)&dcB[l15 * 264 + ks * 32 + quad * 8];
      uint4 bu = *(const uint4*)(WdTm + (size_t)((ks * 8 + nt) * 64 + l) * 8);
      acc = __builtin_amdgcn_mfma_f32_16x16x32_bf16(
          __builtin_bit_cast(bf16x8, au), __builtin_bit_cast(bf16x8, bu), acc, 0, 0, 0);
    }
    int n = nt * 16 + l15;
    #pragma unroll
    for (int r = 0; r < 4; ++r)
      adG[(size_t)(b0 + quad * 4 + r) * 128 + n] = f2bfu(acc[r]);
  }
}

// ---------------------------------------------------------------- per-step attention (wave-private)
// 1024 blocks x 256 thr (8 blocks/CU -> 32 waves/CU). Wave w owns batch b0+w end-to-end:
// full-k score (no cross-wave combine), softmax without max-subtract (|e|<=sum|v_d|~5,
// validated numerically in R11), beta in-register, ctx beta via one __shfl per s-group.
// One barrier total (post-stage).
__global__ __launch_bounds__(256, 8) void attn_step_kernel(
    const unsigned char* __restrict__ AETf8, const unsigned char* __restrict__ EHf8,
    const unsigned short* __restrict__ adG, const float* __restrict__ v_d_g,
    unsigned short* __restrict__ ctxG) {
  __shared__ unsigned short adL[4][128];
  __shared__ float vdL[128];

  const int tid = threadIdx.x;
  const int l = tid & 63, w = tid >> 6;
  const int b = blockIdx.x * 4 + w;
  const int quad = l >> 4, l15 = l & 15;

  if (l < 16)
    *(uint4*)&adL[w][l * 8] = *(const uint4*)(adG + (size_t)b * 128 + l * 8);
  if (tid < 32)
    *(float4*)&vdL[tid * 4] = *(const float4*)(v_d_g + tid * 4);
  __syncthreads();

  // ---- score (lane = s, full k)
  const unsigned char* aet = AETf8 + (size_t)b * 8192;
  float e = 0.f;
  #pragma unroll
  for (int kb = 0; kb < 16; ++kb) {
    uint2 av = *(const uint2*)(aet + kb * 512 + l * 8);
    uint4 ad8 = *(const uint4*)&adL[w][kb * 8];
    float4 v0 = *(const float4*)&vdL[kb * 8];
    float4 v1 = *(const float4*)&vdL[kb * 8 + 4];
    e += fast_tanh(bf_lo(ad8.x) + f8tof(av.x))       * v0.x;
    e += fast_tanh(bf_hi(ad8.x) + f8tof(av.x >> 8))  * v0.y;
    e += fast_tanh(bf_lo(ad8.y) + f8tof(av.x >> 16)) * v0.z;
    e += fast_tanh(bf_hi(ad8.y) + f8tof(av.x >> 24)) * v0.w;
    e += fast_tanh(bf_lo(ad8.z) + f8tof(av.y))       * v1.x;
    e += fast_tanh(bf_hi(ad8.z) + f8tof(av.y >> 8))  * v1.y;
    e += fast_tanh(bf_lo(ad8.w) + f8tof(av.y >> 16)) * v1.z;
    e += fast_tanh(bf_hi(ad8.w) + f8tof(av.y >> 24)) * v1.w;
  }
  float ex = __expf(e);           // |e| <= sum|v_d| — no max-subtract needed
  float ss = ex;
  #pragma unroll
  for (int off = 32; off; off >>= 1) ss += __shfl_xor(ss, off, 64);
  const float bet = __fdividef(ex, ss);   // lane l holds beta[s=l]

  // ---- context: lanes cover i = l15*8..+8; quads cover s-partials; beta via shfl
  const unsigned char* base = EHf8 + (size_t)b * 8192;
  float a[8];
  #pragma unroll
  for (int r = 0; r < 8; ++r) a[r] = 0.f;
  #pragma unroll
  for (int it = 0; it < 16; ++it) {
    int sl = it * 4 + quad;
    uint2 ev = *(const uint2*)(base + sl * 128 + l15 * 8);
    float bt = __shfl(bet, sl, 64);
    a[0] += bt * f8tof(ev.x);       a[1] += bt * f8tof(ev.x >> 8);
    a[2] += bt * f8tof(ev.x >> 16); a[3] += bt * f8tof(ev.x >> 24);
    a[4] += bt * f8tof(ev.y);       a[5] += bt * f8tof(ev.y >> 8);
    a[6] += bt * f8tof(ev.y >> 16); a[7] += bt * f8tof(ev.y >> 24);
  }
  #pragma unroll
  for (int r = 0; r < 8; ++r) {
    a[r] += __shfl_xor(a[r], 16, 64);
    a[r] += __shfl_xor(a[r], 32, 64);
  }
  if (quad == 0) {
    uint4 pk;
    pk.x = pack_bf(a[0], a[1]); pk.y = pack_bf(a[2], a[3]);
    pk.z = pack_bf(a[4], a[5]); pk.w = pack_bf(a[6], a[7]);
    *(uint4*)(ctxG + (size_t)b * 128 + l15 * 8) = pk;
  }
}

// ---------------------------------------------------------------- per-step GEMM (R9-exact)
__global__ __launch_bounds__(512, 2) void gemm_step_kernel(
    const float* __restrict__ ws,
    const unsigned short* __restrict__ dG_in, float* __restrict__ cG,
    const unsigned short* __restrict__ ctxG,
    const unsigned short* __restrict__ WdTm, const unsigned short* __restrict__ WdecTm,
    unsigned short* __restrict__ dG_out, unsigned short* __restrict__ adG,
    float* __restrict__ pvsG,
    const float* __restrict__ b_out_g, const float* __restrict__ smean_g,
    const float* __restrict__ sstd_g, const float* __restrict__ pmean_g,
    float* __restrict__ out, int hz) {
  __shared__ unsigned short gA[16 * 296];
  __shared__ unsigned short dcB[16 * 264];
  __shared__ float pd[16 * 3 * 8];
  __shared__ float pc[16 * 3 * 4];

  const int tid = threadIdx.x;
  const int b0 = blockIdx.x * 16;
  const int l = tid & 63, w = tid >> 6;
  const int quad = l >> 4, l15 = l & 15;

  if (tid < 256) {
    int m = tid >> 4, i0 = (tid & 15) * 8;
    *(uint4*)&gA[m * 296 + i0] = *(const uint4*)(dG_in + (size_t)(b0 + m) * 128 + i0);
  } else {
    int t = tid - 256;
    int m = t >> 4, i0 = (t & 15) * 8;
    *(uint4*)&gA[m * 296 + 128 + i0] = *(const uint4*)(ctxG + (size_t)(b0 + m) * 128 + i0);
  }
  if (tid < 496) { int mm = tid / 31, r = tid % 31; gA[mm * 296 + 265 + r] = 0; }
  if (tid < 48) {
    int m = tid / 3, jj = tid % 3;
    const float* P = pvsG + (size_t)(b0 + m) * 12;
    float sm = smean_g[jj], ss = sstd_g[jj], pm = pmean_g[jj];
    gA[m * 296 + 256 + jj]     = f2bfu(P[jj] - pm);
    gA[m * 296 + 256 + 3 + jj] = f2bfu((P[3 + jj] - sm) / ss);
    gA[m * 296 + 256 + 6 + jj] = f2bfu(P[6 + jj] / ss);
  }
  __syncthreads();

  {
    uint4 af[9];
    #pragma unroll
    for (int ks = 0; ks < 9; ++ks)
      af[ks] = *(const uint4*)&gA[l15 * 296 + ks * 32 + quad * 8];
    const int is = w, i = is * 16 + l15;
    float bb[4], wd[3];
    #pragma unroll
    for (int q = 0; q < 4; ++q) bb[q] = ws[OFF_BDEC + q * 128 + i];
    #pragma unroll
    for (int jj = 0; jj < 3; ++jj) wd[jj] = ws[OFF_WOUTT + i * 3 + jj];
    f32x4 g4[4];
    #pragma unroll
    for (int q = 0; q < 4; ++q) {
      f32x4 acc = {0.f, 0.f, 0.f, 0.f};
      #pragma unroll
      for (int ks = 0; ks < 9; ++ks) {
        uint4 bu = *(const uint4*)(WdecTm + (size_t)(((is * 4 + q) * 9 + ks) * 64 + l) * 8);
        acc = __builtin_amdgcn_mfma_f32_16x16x32_bf16(
            __builtin_bit_cast(bf16x8, af[ks]), __builtin_bit_cast(bf16x8, bu), acc, 0, 0, 0);
      }
      g4[q] = acc;
    }
    float pr[4][3];
    #pragma unroll
    for (int r = 0; r < 4; ++r) {
      int m = quad * 4 + r;
      float gi = g4[0][r] + bb[0];
      float gf = g4[1][r] + bb[1];
      float gg = g4[2][r] + bb[2];
      float go = g4[3][r] + bb[3];
      float co = cG[(size_t)(b0 + m) * 128 + i];
      float cn = sigf(gf) * co + sigf(gi) * fast_tanh(gg);
      float hn = sigf(go) * fast_tanh(cn);
      cG[(size_t)(b0 + m) * 128 + i] = cn;
      unsigned short hb = f2bfu(hn);
      dG_out[(size_t)(b0 + m) * 128 + i] = hb;
      dcB[m * 264 + i] = hb;
      dcB[m * 264 + 128 + i] = f2bfu(cn);
      pr[r][0] = hn * wd[0]; pr[r][1] = hn * wd[1]; pr[r][2] = hn * wd[2];
    }
    #pragma unroll
    for (int r = 0; r < 4; ++r)
      #pragma unroll
      for (int jj = 0; jj < 3; ++jj) {
        float v = pr[r][jj];
        #pragma unroll
        for (int off = 8; off; off >>= 1) v += __shfl_xor(v, off, 64);
        pr[r][jj] = v;
      }
    if (l15 == 0) {
      #pragma unroll
      for (int r = 0; r < 4; ++r)
        #pragma unroll
        for (int jj = 0; jj < 3; ++jj)
          pd[((quad * 4 + r) * 3 + jj) * 8 + is] = pr[r][jj];
    }
  }
  __syncthreads();

  {
    const int nt = w;
    f32x4 acc = {0.f, 0.f, 0.f, 0.f};
    #pragma unroll
    for (int ks = 0; ks < 8; ++ks) {
      uint4 au = *(const uint4*)&dcB[l15 * 264 + ks * 32 + quad * 8];
      uint4 bu = *(const uint4*)(WdTm + (size_t)((ks * 8 + nt) * 64 + l) * 8);
      acc = __builtin_amdgcn_mfma_f32_16x16x32_bf16(
          __builtin_bit_cast(bf16x8, au), __builtin_bit_cast(bf16x8, bu), acc, 0, 0, 0);
    }
    int n = nt * 16 + l15;
    #pragma unroll
    for (int r = 0; r < 4; ++r) {
      int m = quad * 4 + r;
      adG[(size_t)(b0 + m) * 128 + n] = f2bfu(acc[r]);
    }
  }
  if (tid < 192) {
    int m = tid / 12, jj = (tid % 12) / 4, part = tid % 4;
    int k0 = part * 32;
    float acc = 0.f;
    for (int k = k0; k < k0 + 32; ++k) {
      __hip_bfloat16 hv = *(__hip_bfloat16*)&gA[m * 296 + 128 + k];
      acc += __bfloat162float(hv) * ws[OFF_WOUTT + 384 + k * 3 + jj];
    }
    pc[(m * 3 + jj) * 4 + part] = acc;
  }
  __syncthreads();

  if (tid < 48) {
    int m = tid / 3, jj = tid % 3;
    float s = b_out_g[jj];
    #pragma unroll
    for (int p = 0; p < 4; ++p) s += pc[(m * 3 + jj) * 4 + p];
    #pragma unroll
    for (int is = 0; is < 8; ++is) s += pd[(m * 3 + jj) * 8 + is];
    float pacc = s * sstd_g[jj];
    float* P = pvsG + (size_t)(b0 + m) * 12;
    float pos = P[jj], vel = P[3 + jj], acc = P[6 + jj];
    float ppred = pos + vel * DT_ + 0.5f * acc * DT_ * DT_;
    float vnew  = vel + 0.5f * (acc + pacc) * DT_;
    size_t ob = ((size_t)(b0 + m) * HZ_ + hz) * 9;
    out[ob + jj] = ppred; out[ob + 3 + jj] = vnew; out[ob + 6 + jj] = pacc;
    P[jj] = ppred; P[3 + jj] = vnew; P[6 + jj] = pacc;
  }
}

// ---------------------------------------------------------------- launch
extern "C" void kernel_launch(void* const* d_in, const int* in_sizes, int n_in,
                              void* d_out, int out_size, void* d_ws, size_t ws_size,
                              hipStream_t stream) {
  (void)in_sizes; (void)n_in; (void)out_size; (void)ws_size;
  const float* x      = (const float*)d_in[0];
  const float* Wih_e  = (const float*)d_in[1];
  const float* Whh_e  = (const float*)d_in[2];
  const float* bih_e  = (const float*)d_in[3];
  const float* bhh_e  = (const float*)d_in[4];
  const float* W_e    = (const float*)d_in[5];
  const float* V_e    = (const float*)d_in[6];
  const float* v_e    = (const float*)d_in[7];
  const float* W_d    = (const float*)d_in[8];
  const float* V_d    = (const float*)d_in[9];
  const float* v_d    = (const float*)d_in[10];
  const float* Wih_d  = (const float*)d_in[11];
  const float* Whh_d  = (const float*)d_in[12];
  const float* bih_d  = (const float*)d_in[13];
  const float* bhh_d  = (const float*)d_in[14];
  const float* W_out  = (const float*)d_in[15];
  const float* b_out  = (const float*)d_in[16];
  const float* smean  = (const float*)d_in[17];
  const float* sstd   = (const float*)d_in[18];
  const float* pmean  = (const float*)d_in[19];

  float* ws = (float*)d_ws;
  float* pvsG = ws;                                           // over dead encoder tables
  unsigned short* WeTm   = (unsigned short*)(ws + OFF_WET);
  unsigned short* WencTm = (unsigned short*)(ws + OFF_WENCT);
  unsigned short* WdTm   = (unsigned short*)(ws + OFF_WDT);
  unsigned short* WdecTm = (unsigned short*)(ws + OFF_WDECT);
  unsigned short* VdTm   = (unsigned short*)(ws + OFF_VDT);
  unsigned short* dG     = (unsigned short*)(ws + OFF_DECD);
  unsigned short* ctxG   = dG + 524288;
  float* cG = ws + OFF_DECC;
  unsigned short* ub  = (unsigned short*)(ws + F32_TOTAL);
  unsigned short* EH  = ub;
  unsigned char*  AETf8 = (unsigned char*)(ub + 33554432);
  unsigned char*  EHf8  = AETf8 + (size_t)B_ * 8192;
  unsigned short* adG = ub + 67108864;
  float* out = (float*)d_out;

  prep_kernel<<<(PREP_N + 255) / 256, 256, 0, stream>>>(
      Wih_e, Whh_e, bih_e, bhh_e, W_e, V_e, W_d, V_d,
      Wih_d, Whh_d, bih_d, bhh_d, W_out, ws);
  prep_mfma_kernel<<<(32768 + 147456 + 255) / 256, 256, 0, stream>>>(
      W_d, Wih_d, Whh_d, WdTm, WdecTm);
  prep_enc_mfma_kernel<<<(16384 + 81920 + 16384 + 255) / 256, 256, 0, stream>>>(
      W_e, Wih_e, Whh_e, V_d, WeTm, WencTm, VdTm);
  encoder_mfma_kernel<<<B_ / 16, 512, 0, stream>>>(
      x, ws, v_e, WeTm, WencTm, (__hip_bfloat16*)EH, dG, cG);
  attnenc_mfma_kernel<<<B_ / 4, 256, 0, stream>>>(EH, VdTm, AETf8, EHf8);
  init_dec_kernel<<<B_ / 16, 256, 0, stream>>>(
      x, dG, cG, WdTm, smean, sstd, pmean, adG, pvsG);
  for (int hz = 0; hz < HZ_; ++hz) {
    attn_step_kernel<<<B_ / 4, 256, 0, stream>>>(AETf8, EHf8, adG, v_d, ctxG);
    gemm_step_kernel<<<B_ / 16, 512, 0, stream>>>(
        ws, dG, cG, ctxG, WdTm, WdecTm, dG, adG, pvsG,
        b_out, smean, sstd, pmean, out, hz);
  }
}